// Round 3
// baseline (198.129 us; speedup 1.0000x reference)
//
#include <hip/hip_runtime.h>
#include <hip/hip_bf16.h>

#define B_  8
#define Q_  32
#define LE_ 128
#define D_  512
#define P_  32
#define A_  128

typedef __attribute__((ext_vector_type(8))) short short8_t;   // 8 bf16 (4 VGPRs)
typedef __attribute__((ext_vector_type(4))) float floatx4_t;  // 4 fp32 acc

typedef const __attribute__((address_space(1))) unsigned int glb_uint;
typedef __attribute__((address_space(3))) unsigned int lds_uint;
#define GLD16(g, s) __builtin_amdgcn_global_load_lds((glb_uint*)(g), (lds_uint*)(s), 16, 0, 0)

// fp32 -> bf16 round-to-nearest-even, raw bits
__device__ __forceinline__ short f2bf(float x) {
    unsigned u = __float_as_uint(x);
    unsigned r = (u + 0x7fffu + ((u >> 16) & 1u)) >> 16;
    return (short)r;
}
__device__ __forceinline__ float bf2f(short s) {
    return __uint_as_float(((unsigned)(unsigned short)s) << 16);
}

// ---------------- K0: prep = convert X/W fp32->bf16  +  ws (EW)  +  zero gsums ---
// blocks [0,8192): X convert; [8192,8224): W convert; [8224,8480): ws per (b,p)
__global__ __launch_bounds__(256) void prep_kernel(
    const float* __restrict__ X, const float* __restrict__ W,
    const float* __restrict__ s_j, const float* __restrict__ Ws_w,
    const float* __restrict__ Ws_b,
    short* __restrict__ Xb, short* __restrict__ Wb,
    float* __restrict__ EW, float* __restrict__ gsums) {
    __shared__ float s_row[D_];
    int b = blockIdx.x;
    int tid = threadIdx.x;
    if (b < 8224) {
        const float* src;
        short* dst;
        size_t base;
        if (b < 8192) {
            base = ((size_t)b * 256 + tid) * 8;
            src = X + base; dst = Xb + base;
        } else {
            base = ((size_t)(b - 8192) * 256 + tid) * 8;
            src = W + base; dst = Wb + base;
        }
        float4 v0 = ((const float4*)src)[0];
        float4 v1 = ((const float4*)src)[1];
        short8_t s;
        s[0] = f2bf(v0.x); s[1] = f2bf(v0.y); s[2] = f2bf(v0.z); s[3] = f2bf(v0.w);
        s[4] = f2bf(v1.x); s[5] = f2bf(v1.y); s[6] = f2bf(v1.z); s[7] = f2bf(v1.w);
        *(short8_t*)dst = s;
        return;
    }
    int bp = b - 8224;
    if (b == 8224) gsums[tid] = 0.0f;   // 256 entries, 256 threads
    const float* src = s_j + (size_t)bp * D_;
    for (int i = tid; i < D_; i += 256) s_row[i] = src[i];
    __syncthreads();
    if (tid < 128) {
        int a = tid;
        const float4* w4 = (const float4*)(Ws_w + (size_t)a * D_);
        const float4* s4 = (const float4*)s_row;
        float acc = 0.0f;
#pragma unroll 8
        for (int i = 0; i < D_ / 4; ++i) {
            float4 w = w4[i];
            float s = w.x * s4[i].x + w.y * s4[i].y + w.z * s4[i].z + w.w * s4[i].w;
            acc += s;
        }
        EW[bp * A_ + a] = __expf(2.0f * (acc + Ws_b[a]));
    }
}

// ---------------- K1: score kernel, per (bq, t-half) ------------------------------
// blk = bq*2 + h; t range [h*64, h*64+64)
// Phase 1: uh[t=64][a=128] = Xb[bq, t-half]·Wb^T (K=512) via MFMA + GLD16
// Phase 2: EU = bf16(exp(2 uh)) -> LDS; load EW, n2v, mask
// Phase 3: w[p][t] = bf16(exp(-sum_a 2 v_a /(1+EU·EW))) (mask->0) -> global wglob
// Sums:    per-p wave-shuffle reduce -> global atomic gsums[b,p]
#define EUP_ 136   // EU row stride (shorts)
#define EWP_ 132   // EW row stride (floats)

__global__ __launch_bounds__(512, 4) void score_kernel(
    const short* __restrict__ Xb, const short* __restrict__ Wb,
    const float* __restrict__ EW, const float* __restrict__ v_w,
    const int* __restrict__ exp_mask, float* __restrict__ gsums,
    short* __restrict__ wglob) {
    __shared__ short uA[12288];        // union: As(4096)+Bs(8192) staging / EU(64*136=8704)
    __shared__ float ew_s[32 * EWP_];  // 16896 B
    __shared__ float n2v[128];
    __shared__ int   mask_s[64];

    int blk = blockIdx.x;
    int bq = blk >> 1, t0 = (blk & 1) * 64;
    int b  = bq >> 5;
    int tid = threadIdx.x;
    int wave = tid >> 6, lane = tid & 63;
    int qd = lane >> 4, lr = lane & 15;

    short* As = uA;            // 4096 shorts (64 rows x 64 k)
    short* Bs = uA + 4096;     // 8192 shorts (128 rows x 64 k)

    // ---- phase 1: uh GEMM (M=64, N=128, K=512). wave grid 2 (M) x 4 (N) ----
    int m0 = (wave >> 2) * 32, n0 = (wave & 3) * 32;
    int cA = lane & 7;
    int rowA  = wave * 8 + (lane >> 3);     // 64 A rows, 1 GLD16 issue/wave
    int rowB0 = wave * 16 + (lane >> 3);    // 128 B rows, 2 issues/wave

    floatx4_t acc[2][2];
#pragma unroll
    for (int i = 0; i < 2; ++i)
#pragma unroll
        for (int j = 0; j < 2; ++j) acc[i][j] = (floatx4_t){0.f, 0.f, 0.f, 0.f};

    for (int kt = 0; kt < 8; ++kt) {
        int k0 = kt * 64;
        __syncthreads();
        GLD16(Xb + (size_t)(bq * 128 + t0 + rowA) * D_ + k0 + ((cA ^ (rowA & 7)) * 8),
              As + wave * 512);
#pragma unroll
        for (int u = 0; u < 2; ++u) {
            int n = rowB0 + u * 8;
            GLD16(Wb + (size_t)n * D_ + k0 + ((cA ^ (n & 7)) * 8),
                  Bs + (wave * 2 + u) * 512);
        }
        __syncthreads();
#pragma unroll
        for (int ks = 0; ks < 2; ++ks) {
            int cr = (ks * 4 + qd) ^ (lr & 7);
            short8_t af[2], bfr[2];
#pragma unroll
            for (int i = 0; i < 2; ++i)
                af[i] = *(const short8_t*)(As + (m0 + i * 16 + lr) * 64 + cr * 8);
#pragma unroll
            for (int j = 0; j < 2; ++j)
                bfr[j] = *(const short8_t*)(Bs + (n0 + j * 16 + lr) * 64 + cr * 8);
#pragma unroll
            for (int i = 0; i < 2; ++i)
#pragma unroll
                for (int j = 0; j < 2; ++j)
                    acc[i][j] = __builtin_amdgcn_mfma_f32_16x16x32_bf16(af[i], bfr[j], acc[i][j], 0, 0, 0);
        }
    }
    __syncthreads();   // staging LDS dead -> becomes EU

    // ---- phase 2: EU to LDS (bf16), load EW / n2v / mask ----
#pragma unroll
    for (int i = 0; i < 2; ++i)
#pragma unroll
        for (int j = 0; j < 2; ++j)
#pragma unroll
            for (int r = 0; r < 4; ++r) {
                int t = m0 + i * 16 + qd * 4 + r;      // [0,64)
                int a = n0 + j * 16 + lr;              // [0,128)
                uA[t * EUP_ + a] = f2bf(__expf(2.0f * acc[i][j][r]));
            }
#pragma unroll
    for (int u = 0; u < 2; ++u) {
        int c = tid * 2 + u;              // 1024 float4 = 4096 floats
        int p = c >> 5, seg = c & 31;
        *(float4*)&ew_s[p * EWP_ + seg * 4] =
            *(const float4*)&EW[(size_t)(b * P_ + p) * A_ + seg * 4];
    }
    if (tid < 32) {
        float4 v = *(const float4*)(v_w + tid * 4);
        v.x *= -2.0f; v.y *= -2.0f; v.z *= -2.0f; v.w *= -2.0f;
        *(float4*)&n2v[tid * 4] = v;
    }
    if (tid < 64) mask_s[tid] = exp_mask[bq * LE_ + t0 + tid];
    __syncthreads();

    // ---- phase 3: score. thread = (t = tid&63, pg = tid>>6); 4 p per thread ----
    {
        int t = tid & 63, pg = tid >> 6;
        float acc4[4];
#pragma unroll
        for (int j = 0; j < 4; ++j) acc4[j] = 0.0f;
        for (int a8 = 0; a8 < 16; ++a8) {
            short8_t e8 = *(const short8_t*)&uA[t * EUP_ + a8 * 8];
            float eu[8];
#pragma unroll
            for (int k = 0; k < 8; ++k) eu[k] = bf2f(e8[k]);
            float4 nv0 = *(const float4*)&n2v[a8 * 8];
            float4 nv1 = *(const float4*)&n2v[a8 * 8 + 4];
            float nv[8] = {nv0.x, nv0.y, nv0.z, nv0.w, nv1.x, nv1.y, nv1.z, nv1.w};
#pragma unroll
            for (int j = 0; j < 4; ++j) {
                int p = pg * 4 + j;
                float4 w0 = *(const float4*)&ew_s[p * EWP_ + a8 * 8];
                float4 w1 = *(const float4*)&ew_s[p * EWP_ + a8 * 8 + 4];
                float ww[8] = {w0.x, w0.y, w0.z, w0.w, w1.x, w1.y, w1.z, w1.w};
#pragma unroll
                for (int k = 0; k < 8; ++k)
                    acc4[j] = fmaf(nv[k], __builtin_amdgcn_rcpf(fmaf(eu[k], ww[k], 1.0f)), acc4[j]);
            }
        }
        int mk = mask_s[t];
        short* wg = wglob + (size_t)bq * (P_ * LE_);
        float sums[4];
#pragma unroll
        for (int j = 0; j < 4; ++j) {
            float ee = mk ? __expf(acc4[j]) : 0.0f;
            short v = f2bf(ee);
            wg[(pg * 4 + j) * LE_ + t0 + t] = v;   // coalesced over t within wave
            sums[j] = bf2f(v);
        }
        // per-p sum: full-wave butterfly (t spans exactly the 64 lanes of this wave)
#pragma unroll
        for (int j = 0; j < 4; ++j) {
            float s = sums[j];
            s += __shfl_xor(s, 1);
            s += __shfl_xor(s, 2);
            s += __shfl_xor(s, 4);
            s += __shfl_xor(s, 8);
            s += __shfl_xor(s, 16);
            s += __shfl_xor(s, 32);
            if (lane == 0) atomicAdd(&gsums[b * P_ + pg * 4 + j], s);
        }
    }
}

// ---------------- K2: PV kernel, per (bq, d-chunk) -------------------------------
// out[bq,p,d0+d] = rm[b,p] * sum_t w[bq,p,t] * Xb[bq,t,d0+d]
__global__ __launch_bounds__(512, 4) void pv_kernel(
    const short* __restrict__ Xb, const short* __restrict__ wglob,
    const float* __restrict__ gsums, const int* __restrict__ req_mask,
    float* __restrict__ out) {
    __shared__ short pvB[128 * EUP_];   // 34816 B: X^T chunk [d_local][t]
    __shared__ float rm_s[32];

    int blk = blockIdx.x;
    int bq = blk >> 2, chunk = blk & 3;
    int b = bq >> 5;
    int d0 = chunk * 128;
    int tid = threadIdx.x;
    int wave = tid >> 6, lane = tid & 63;
    int qd = lane >> 4, lr = lane & 15;

    // rm[p] = req_mask ? 1/gsum : 0 (gsums complete: stream-ordered after score)
    if (tid < 32) {
        int bp = b * P_ + tid;
        float g = gsums[bp];
        rm_s[tid] = req_mask[bp] ? __builtin_amdgcn_rcpf(g) : 0.0f;
    }

    // A-fragments straight from global w (16B/lane, matches MFMA A layout)
    const short* wg = wglob + (size_t)bq * (P_ * LE_);
    short8_t afv[2][4];
#pragma unroll
    for (int i = 0; i < 2; ++i)
#pragma unroll
        for (int ks = 0; ks < 4; ++ks)
            afv[i][ks] = *(const short8_t*)&wg[(i * 16 + lr) * LE_ + ks * 32 + qd * 8];

    // stage: transpose Xb[t][d0..d0+128) -> pvB[d_local][t]
    int tt = tid >> 2, dseg = (tid & 3) * 32;
    const short8_t* g = (const short8_t*)(Xb + (size_t)(bq * 128 + tt) * D_ + d0 + dseg);
    short8_t xs0 = g[0], xs1 = g[1], xs2 = g[2], xs3 = g[3];
#pragma unroll
    for (int e = 0; e < 8; ++e) {
        pvB[(dseg + 0 + e) * EUP_ + tt]  = xs0[e];
        pvB[(dseg + 8 + e) * EUP_ + tt]  = xs1[e];
        pvB[(dseg + 16 + e) * EUP_ + tt] = xs2[e];
        pvB[(dseg + 24 + e) * EUP_ + tt] = xs3[e];
    }
    __syncthreads();

    floatx4_t accp[2];
    accp[0] = (floatx4_t){0.f, 0.f, 0.f, 0.f};
    accp[1] = (floatx4_t){0.f, 0.f, 0.f, 0.f};
#pragma unroll
    for (int ks = 0; ks < 4; ++ks) {
        short8_t bfr = *(const short8_t*)&pvB[(wave * 16 + lr) * EUP_ + ks * 32 + qd * 8];
        accp[0] = __builtin_amdgcn_mfma_f32_16x16x32_bf16(afv[0][ks], bfr, accp[0], 0, 0, 0);
        accp[1] = __builtin_amdgcn_mfma_f32_16x16x32_bf16(afv[1][ks], bfr, accp[1], 0, 0, 0);
    }
    // C/D: col = lane&15 (d), row = qd*4+r (p)
#pragma unroll
    for (int i = 0; i < 2; ++i)
#pragma unroll
        for (int r = 0; r < 4; ++r) {
            int p = i * 16 + qd * 4 + r;
            __builtin_nontemporal_store(
                accp[i][r] * rm_s[p],
                &out[((size_t)bq * P_ + p) * D_ + d0 + wave * 16 + lr]);
        }
}

extern "C" void kernel_launch(void* const* d_in, const int* in_sizes, int n_in,
                              void* d_out, int out_size, void* d_ws, size_t ws_size,
                              hipStream_t stream) {
    const float* exp_tokens = (const float*)d_in[0];
    const int*   exp_mask   = (const int*)d_in[1];
    const float* s_j        = (const float*)d_in[2];
    const int*   req_mask   = (const int*)d_in[3];
    const float* Ws_w       = (const float*)d_in[4];
    const float* Ws_b       = (const float*)d_in[5];
    const float* U_w        = (const float*)d_in[6];
    const float* v_w        = (const float*)d_in[7];
    float* out = (float*)d_out;

    float* EW    = (float*)d_ws;                          // 32768 floats
    float* gsums = EW + B_ * P_ * A_;                     // 256 floats
    short* Xb    = (short*)(gsums + 256);                 // 16.7M shorts
    short* Wb    = Xb + (size_t)B_ * Q_ * LE_ * D_;       // 64K shorts
    short* wglob = Wb + (size_t)A_ * D_;                  // 1M shorts (2 MB)

    prep_kernel<<<dim3(8192 + 32 + 256), dim3(256), 0, stream>>>(
        exp_tokens, U_w, s_j, Ws_w, Ws_b, Xb, Wb, EW, gsums);
    score_kernel<<<dim3(B_ * Q_ * 2), dim3(512), 0, stream>>>(
        Xb, Wb, EW, v_w, exp_mask, gsums, wglob);
    pv_kernel<<<dim3(B_ * Q_ * 4), dim3(512), 0, stream>>>(
        Xb, wglob, gsums, req_mask, out);
}

// Round 4
// 155.696 us; speedup vs baseline: 1.2725x; 1.2725x over previous
//
#include <hip/hip_runtime.h>
#include <hip/hip_bf16.h>

#define B_  8
#define Q_  32
#define LE_ 128
#define D_  512
#define P_  32
#define A_  128

typedef __attribute__((ext_vector_type(8))) short short8_t;   // 8 bf16 (4 VGPRs)
typedef __attribute__((ext_vector_type(4))) float floatx4_t;  // 4 fp32 acc

typedef const __attribute__((address_space(1))) unsigned int glb_uint;
typedef __attribute__((address_space(3))) unsigned int lds_uint;
#define GLD16(g, s) __builtin_amdgcn_global_load_lds((glb_uint*)(g), (lds_uint*)(s), 16, 0, 0)

// fp32 -> bf16 round-to-nearest-even, raw bits
__device__ __forceinline__ short f2bf(float x) {
    unsigned u = __float_as_uint(x);
    unsigned r = (u + 0x7fffu + ((u >> 16) & 1u)) >> 16;
    return (short)r;
}
__device__ __forceinline__ float bf2f(short s) {
    return __uint_as_float(((unsigned)(unsigned short)s) << 16);
}
__device__ __forceinline__ short8_t cvt8(float4 a, float4 b) {
    short8_t s;
    s[0] = f2bf(a.x); s[1] = f2bf(a.y); s[2] = f2bf(a.z); s[3] = f2bf(a.w);
    s[4] = f2bf(b.x); s[5] = f2bf(b.y); s[6] = f2bf(b.z); s[7] = f2bf(b.w);
    return s;
}

// ---------------- K0: prep -------------------------------------------------------
// blocks [0,256): ws (EW) + gsums zero   <- FIRST so latency-bound blocks overlap
// blocks [256,2304): X convert, 4 x 32B-chunks per thread (ILP)
// blocks [2304,2336): W convert, 1 chunk per thread
__global__ __launch_bounds__(256) void prep_kernel(
    const float* __restrict__ X, const float* __restrict__ W,
    const float* __restrict__ s_j, const float* __restrict__ Ws_w,
    const float* __restrict__ Ws_b,
    short* __restrict__ Xb, short* __restrict__ Wb,
    float* __restrict__ EW, float* __restrict__ gsums) {
    __shared__ float s_row[D_];
    int blk = blockIdx.x;
    int tid = threadIdx.x;
    if (blk < 256) {
        int bp = blk;
        if (blk == 0) gsums[tid] = 0.0f;   // 256 entries, 256 threads
        const float* src = s_j + (size_t)bp * D_;
        for (int i = tid; i < D_; i += 256) s_row[i] = src[i];
        __syncthreads();
        if (tid < 128) {
            int a = tid;
            const float4* w4 = (const float4*)(Ws_w + (size_t)a * D_);
            const float4* s4 = (const float4*)s_row;
            float acc = 0.0f;
#pragma unroll 8
            for (int i = 0; i < D_ / 4; ++i) {
                float4 w = w4[i];
                acc += w.x * s4[i].x + w.y * s4[i].y + w.z * s4[i].z + w.w * s4[i].w;
            }
            EW[bp * A_ + a] = __expf(2.0f * (acc + Ws_b[a]));
        }
        return;
    }
    int cb = blk - 256;
    if (cb < 2048) {
        // X: 2048 blocks x 256 threads x 4 groups of 8 floats = 16,777,216 floats
        size_t g = (size_t)cb * 1024 + tid;    // group id; +256 per chunk
        float4 v[8];
#pragma unroll
        for (int u = 0; u < 4; ++u) {
            const float4* s4 = (const float4*)(X + (g + (size_t)u * 256) * 8);
            v[u * 2]     = s4[0];
            v[u * 2 + 1] = s4[1];
        }
#pragma unroll
        for (int u = 0; u < 4; ++u)
            *(short8_t*)(Xb + (g + (size_t)u * 256) * 8) = cvt8(v[u * 2], v[u * 2 + 1]);
    } else {
        // W: 32 blocks x 256 threads x 1 group = 65,536 floats
        size_t g = (size_t)(cb - 2048) * 256 + tid;
        const float4* s4 = (const float4*)(W + g * 8);
        float4 a = s4[0], b = s4[1];
        *(short8_t*)(Wb + g * 8) = cvt8(a, b);
    }
}

// ---------------- K1: score kernel, per-bq (R2-proven shape) ---------------------
// Phase 1: uh[t=128][a=128] = Xb[bq]·Wb^T (K=512) via MFMA + GLD16
// Phase 2: EU = bf16(exp(2 uh)) -> LDS; load EW, n2v, mask
// Phase 3: score -> w[p][t] = bf16(exp(-sum_a 2 v_a /(1+EU·EW))) (mask->0)
//          -> write w to GLOBAL (2 MB total, bf16), coalesced
// Sums:    per-p sum of w -> global atomic gsums[b,p]
#define EUP_ 136   // EU / pvB row stride (shorts)
#define EWP_ 132   // EW row stride (floats)
#define WPP_ 136   // w_lds row stride (shorts)

__global__ __launch_bounds__(512, 1) void score_kernel(
    const short* __restrict__ Xb, const short* __restrict__ Wb,
    const float* __restrict__ EW, const float* __restrict__ v_w,
    const int* __restrict__ exp_mask, float* __restrict__ gsums,
    short* __restrict__ wglob) {
    __shared__ short uA[128 * EUP_];   // 34816 B union: {As+Bs staging} / EU
    __shared__ float ew_s[32 * EWP_];  // 16896 B
    __shared__ short w_s[32 * WPP_];   // 8704 B
    __shared__ float n2v[128];
    __shared__ int   mask_s[128];

    int bq = blockIdx.x;
    int b  = bq >> 5;
    int tid = threadIdx.x;
    int wave = tid >> 6, lane = tid & 63;
    int qd = lane >> 4, lr = lane & 15;

    short* As = uA;            // 8192 shorts (16 KB)
    short* Bs = uA + 8192;     // 8192 shorts (16 KB)

    // ---- phase 1: uh GEMM ----
    int m0 = (wave >> 1) * 32, n0 = (wave & 1) * 64;
    int cA = lane & 7;
    int row0 = wave * 16 + (lane >> 3);

    floatx4_t acc[2][4];
#pragma unroll
    for (int i = 0; i < 2; ++i)
#pragma unroll
        for (int j = 0; j < 4; ++j) acc[i][j] = (floatx4_t){0.f, 0.f, 0.f, 0.f};

    for (int kt = 0; kt < 8; ++kt) {
        int k0 = kt * 64;
        __syncthreads();
#pragma unroll
        for (int u = 0; u < 2; ++u) {
            int m = row0 + u * 8;
            GLD16(Xb + (size_t)(bq * 128 + m) * D_ + k0 + ((cA ^ (m & 7)) * 8),
                  As + (wave * 2 + u) * 512);
        }
#pragma unroll
        for (int u = 0; u < 2; ++u) {
            int n = row0 + u * 8;
            GLD16(Wb + (size_t)n * D_ + k0 + ((cA ^ (n & 7)) * 8),
                  Bs + (wave * 2 + u) * 512);
        }
        __syncthreads();
#pragma unroll
        for (int ks = 0; ks < 2; ++ks) {
            int cr = (ks * 4 + qd) ^ (lr & 7);
            short8_t af[2], bfr[4];
#pragma unroll
            for (int i = 0; i < 2; ++i)
                af[i] = *(const short8_t*)(As + (m0 + i * 16 + lr) * 64 + cr * 8);
#pragma unroll
            for (int j = 0; j < 4; ++j)
                bfr[j] = *(const short8_t*)(Bs + (n0 + j * 16 + lr) * 64 + cr * 8);
#pragma unroll
            for (int i = 0; i < 2; ++i)
#pragma unroll
                for (int j = 0; j < 4; ++j)
                    acc[i][j] = __builtin_amdgcn_mfma_f32_16x16x32_bf16(af[i], bfr[j], acc[i][j], 0, 0, 0);
        }
    }
    __syncthreads();   // staging LDS dead -> becomes EU

    // ---- phase 2: EU to LDS (bf16), load EW / n2v / mask ----
#pragma unroll
    for (int i = 0; i < 2; ++i)
#pragma unroll
        for (int j = 0; j < 4; ++j)
#pragma unroll
            for (int r = 0; r < 4; ++r) {
                int t = m0 + i * 16 + qd * 4 + r;
                int a = n0 + j * 16 + lr;
                uA[t * EUP_ + a] = f2bf(__expf(2.0f * acc[i][j][r]));
            }
#pragma unroll
    for (int u = 0; u < 2; ++u) {
        int c = tid * 2 + u;              // 1024 float4 = 4096 floats
        int p = c >> 5, seg = c & 31;
        *(float4*)&ew_s[p * EWP_ + seg * 4] =
            *(const float4*)&EW[(size_t)(b * P_ + p) * A_ + seg * 4];
    }
    if (tid < 32) {
        float4 v = *(const float4*)(v_w + tid * 4);
        v.x *= -2.0f; v.y *= -2.0f; v.z *= -2.0f; v.w *= -2.0f;
        *(float4*)&n2v[tid * 4] = v;
    }
    if (tid < 128) mask_s[tid] = exp_mask[bq * LE_ + tid];
    __syncthreads();

    // ---- phase 3: score. thread = (t = tid&127, pg = tid>>7); 8 p per thread ----
    {
        int t = tid & 127, pg = tid >> 7;
        float acc8[8];
#pragma unroll
        for (int j = 0; j < 8; ++j) acc8[j] = 0.0f;
        for (int a8 = 0; a8 < 16; ++a8) {
            short8_t e8 = *(const short8_t*)&uA[t * EUP_ + a8 * 8];
            float eu[8];
#pragma unroll
            for (int k = 0; k < 8; ++k) eu[k] = bf2f(e8[k]);
            float4 nv0 = *(const float4*)&n2v[a8 * 8];
            float4 nv1 = *(const float4*)&n2v[a8 * 8 + 4];
            float nv[8] = {nv0.x, nv0.y, nv0.z, nv0.w, nv1.x, nv1.y, nv1.z, nv1.w};
#pragma unroll
            for (int j = 0; j < 8; ++j) {
                int p = pg * 8 + j;
                float4 w0 = *(const float4*)&ew_s[p * EWP_ + a8 * 8];
                float4 w1 = *(const float4*)&ew_s[p * EWP_ + a8 * 8 + 4];
                float ww[8] = {w0.x, w0.y, w0.z, w0.w, w1.x, w1.y, w1.z, w1.w};
#pragma unroll
                for (int k = 0; k < 8; ++k)
                    acc8[j] = fmaf(nv[k], __builtin_amdgcn_rcpf(fmaf(eu[k], ww[k], 1.0f)), acc8[j]);
            }
        }
        int mk = mask_s[t];
        short* wg = wglob + (size_t)bq * (P_ * LE_);
#pragma unroll
        for (int j = 0; j < 8; ++j) {
            float ee = mk ? __expf(acc8[j]) : 0.0f;
            short v = f2bf(ee);
            w_s[(pg * 8 + j) * WPP_ + t] = v;
            wg[(pg * 8 + j) * LE_ + t] = v;   // coalesced over t within wave
        }
    }
    __syncthreads();   // w_s complete

    // ---- sums: per-p reduce of w_s, one global atomic per p ----
    if (tid < 256) {
        int p = tid >> 3, seg = tid & 7;
        const short* src = w_s + p * WPP_ + seg * 16;
        float s = 0.0f;
#pragma unroll
        for (int k = 0; k < 16; ++k) s += bf2f(src[k]);
        s += __shfl_xor(s, 1);
        s += __shfl_xor(s, 2);
        s += __shfl_xor(s, 4);
        if (seg == 0) atomicAdd(&gsums[b * P_ + p], s);
    }
}

// ---------------- K2: PV kernel, per (bq, d-chunk) -------------------------------
// out[bq,p,d0+d] = rm[b,p] * sum_t w[bq,p,t] * Xb[bq,t,d0+d]
__global__ __launch_bounds__(512, 4) void pv_kernel(
    const short* __restrict__ Xb, const short* __restrict__ wglob,
    const float* __restrict__ gsums, const int* __restrict__ req_mask,
    float* __restrict__ out) {
    __shared__ short pvB[128 * EUP_];   // 34816 B: X^T chunk [d_local][t]
    __shared__ float rm_s[32];

    int blk = blockIdx.x;
    int bq = blk >> 2, chunk = blk & 3;
    int b = bq >> 5;
    int d0 = chunk * 128;
    int tid = threadIdx.x;
    int wave = tid >> 6, lane = tid & 63;
    int qd = lane >> 4, lr = lane & 15;

    // rm[p] = req_mask ? 1/gsum : 0 (gsums complete: stream-ordered after score)
    if (tid < 32) {
        int bp = b * P_ + tid;
        float g = gsums[bp];
        rm_s[tid] = req_mask[bp] ? __builtin_amdgcn_rcpf(g) : 0.0f;
    }

    // A-fragments straight from global w (16B/lane, matches MFMA A layout)
    const short* wg = wglob + (size_t)bq * (P_ * LE_);
    short8_t afv[2][4];
#pragma unroll
    for (int i = 0; i < 2; ++i)
#pragma unroll
        for (int ks = 0; ks < 4; ++ks)
            afv[i][ks] = *(const short8_t*)&wg[(i * 16 + lr) * LE_ + ks * 32 + qd * 8];

    // stage: transpose Xb[t][d0..d0+128) -> pvB[d_local][t]
    int tt = tid >> 2, dseg = (tid & 3) * 32;
    const short8_t* g = (const short8_t*)(Xb + (size_t)(bq * 128 + tt) * D_ + d0 + dseg);
    short8_t xs0 = g[0], xs1 = g[1], xs2 = g[2], xs3 = g[3];
#pragma unroll
    for (int e = 0; e < 8; ++e) {
        pvB[(dseg + 0 + e) * EUP_ + tt]  = xs0[e];
        pvB[(dseg + 8 + e) * EUP_ + tt]  = xs1[e];
        pvB[(dseg + 16 + e) * EUP_ + tt] = xs2[e];
        pvB[(dseg + 24 + e) * EUP_ + tt] = xs3[e];
    }
    __syncthreads();

    floatx4_t accp[2];
    accp[0] = (floatx4_t){0.f, 0.f, 0.f, 0.f};
    accp[1] = (floatx4_t){0.f, 0.f, 0.f, 0.f};
#pragma unroll
    for (int ks = 0; ks < 4; ++ks) {
        short8_t bfr = *(const short8_t*)&pvB[(wave * 16 + lr) * EUP_ + ks * 32 + qd * 8];
        accp[0] = __builtin_amdgcn_mfma_f32_16x16x32_bf16(afv[0][ks], bfr, accp[0], 0, 0, 0);
        accp[1] = __builtin_amdgcn_mfma_f32_16x16x32_bf16(afv[1][ks], bfr, accp[1], 0, 0, 0);
    }
    // C/D: col = lane&15 (d), row = qd*4+r (p)
#pragma unroll
    for (int i = 0; i < 2; ++i)
#pragma unroll
        for (int r = 0; r < 4; ++r) {
            int p = i * 16 + qd * 4 + r;
            __builtin_nontemporal_store(
                accp[i][r] * rm_s[p],
                &out[((size_t)bq * P_ + p) * D_ + d0 + wave * 16 + lr]);
        }
}

extern "C" void kernel_launch(void* const* d_in, const int* in_sizes, int n_in,
                              void* d_out, int out_size, void* d_ws, size_t ws_size,
                              hipStream_t stream) {
    const float* exp_tokens = (const float*)d_in[0];
    const int*   exp_mask   = (const int*)d_in[1];
    const float* s_j        = (const float*)d_in[2];
    const int*   req_mask   = (const int*)d_in[3];
    const float* Ws_w       = (const float*)d_in[4];
    const float* Ws_b       = (const float*)d_in[5];
    const float* U_w        = (const float*)d_in[6];
    const float* v_w        = (const float*)d_in[7];
    float* out = (float*)d_out;

    float* EW    = (float*)d_ws;                          // 32768 floats
    float* gsums = EW + B_ * P_ * A_;                     // 256 floats
    short* Xb    = (short*)(gsums + 256);                 // 16.7M shorts
    short* Wb    = Xb + (size_t)B_ * Q_ * LE_ * D_;       // 64K shorts
    short* wglob = Wb + (size_t)A_ * D_;                  // 1M shorts (2 MB)

    prep_kernel<<<dim3(256 + 2048 + 32), dim3(256), 0, stream>>>(
        exp_tokens, U_w, s_j, Ws_w, Ws_b, Xb, Wb, EW, gsums);
    score_kernel<<<dim3(B_ * Q_), dim3(512), 0, stream>>>(
        Xb, Wb, EW, v_w, exp_mask, gsums, wglob);
    pv_kernel<<<dim3(B_ * Q_ * 4), dim3(512), 0, stream>>>(
        Xb, wglob, gsums, req_mask, out);
}